// Round 9
// baseline (186.127 us; speedup 1.0000x reference)
//
#include <hip/hip_runtime.h>
#include <math.h>

#define Bc 16
#define Nc 1024
#define Fc 256
#define Hc 8
#define Kc 512
#define DOUTc 256
#define EPSc 1e-8f

typedef short v8s __attribute__((ext_vector_type(8)));
typedef float v4f __attribute__((ext_vector_type(4)));

__device__ __forceinline__ float waveReduceSum(float v) {
    v += __shfl_xor(v, 32); v += __shfl_xor(v, 16); v += __shfl_xor(v, 8);
    v += __shfl_xor(v, 4);  v += __shfl_xor(v, 2);  v += __shfl_xor(v, 1);
    return v;
}

__device__ __forceinline__ unsigned short f2bf(float f) {
    unsigned int u = __float_as_uint(f);
    u = (u + 0x7fffu + ((u >> 16) & 1u)) >> 16;   // RNE
    return (unsigned short)u;
}

// CK-style LDS-only barrier: drains lgkmcnt but leaves global loads in flight.
__device__ __forceinline__ void lds_barrier() {
    __builtin_amdgcn_s_waitcnt(0xC07F);   // lgkmcnt(0), vmcnt=63 (no wait), expcnt=7
    __builtin_amdgcn_s_barrier();
}

// ================= fused preprocessing =================
// ranges: [0,64)      k2 row sums, 64 rows/block (+1 folded for cmfma)
//         [64,576)    kpack -> Kp        (B-frag order for cmfma)
//         [576,2624)  qpack -> Qbp       (B-frag order for vmfma)
//         [2624,2656) wpack -> Wp        (B-frag order for ofma)
//         [2656,2658) zero cn + kl
__global__ __launch_bounds__(256) void prep_all(
    const float* __restrict__ Q, const float* __restrict__ keys,
    const float* __restrict__ lin_w,
    float* __restrict__ k2g, unsigned short* __restrict__ Kp,
    unsigned short* __restrict__ Qbp, unsigned short* __restrict__ Wp,
    float* __restrict__ cn, float* __restrict__ klout) {
    __shared__ unsigned short T2[32][66];
    const int bx = blockIdx.x;
    const int tid = threadIdx.x;
    if (bx < 64) {
        int wv = tid >> 6, l = tid & 63;
#pragma unroll 4
        for (int rr = 0; rr < 16; rr++) {
            int row = bx * 64 + wv * 16 + rr;
            float4 v = *(const float4*)(keys + (size_t)row * Fc + l * 4);
            float s = v.x * v.x + v.y * v.y + v.z * v.z + v.w * v.w;
            s = waveReduceSum(s);
            if (l == 0) k2g[row] = s + 1.0f;   // +1 folded: cmfma uses max(d2+1,1)
        }
    } else if (bx < 576) {
        int t = (bx - 64) * 256 + tid;
        int lane = t & 63, ci = t >> 6;
        int ct = ci & 7, ks = (ci >> 3) & 7, wv = (ci >> 6) & 3, h = ci >> 8;
        int qd = lane >> 4, li = lane & 15;
        int col = h * 512 + wv * 128 + ct * 16 + li;
        const float* src = keys + (size_t)col * Fc + ks * 32 + qd * 8;
        float4 a = *(const float4*)src;
        float4 b = *(const float4*)(src + 4);
        *(ushort4*)(Kp + (size_t)t * 8) = make_ushort4(f2bf(a.x), f2bf(a.y), f2bf(a.z), f2bf(a.w));
        *(ushort4*)(Kp + (size_t)t * 8 + 4) = make_ushort4(f2bf(b.x), f2bf(b.y), f2bf(b.z), f2bf(b.w));
    } else if (bx < 2624) {
        int i = bx - 576;
        int n0 = (i & 31) * 32, f0 = ((i >> 5) & 3) * 64, bb = i >> 7;
        {
            int n_l = tid >> 3, f_l = (tid & 7) * 8;
            const float* src = Q + ((size_t)(bb * Nc + n0 + n_l)) * Fc + f0 + f_l;
            float4 a = *(const float4*)src;
            float4 b = *(const float4*)(src + 4);
            T2[n_l][f_l + 0] = f2bf(a.x); T2[n_l][f_l + 1] = f2bf(a.y);
            T2[n_l][f_l + 2] = f2bf(a.z); T2[n_l][f_l + 3] = f2bf(a.w);
            T2[n_l][f_l + 4] = f2bf(b.x); T2[n_l][f_l + 5] = f2bf(b.y);
            T2[n_l][f_l + 6] = f2bf(b.z); T2[n_l][f_l + 7] = f2bf(b.w);
        }
        __syncthreads();
        int c = tid >> 6, L = tid & 63;
        int qd = L >> 4, li = L & 15;
        unsigned short o[8];
#pragma unroll
        for (int j = 0; j < 8; j++) o[j] = T2[qd * 8 + j][c * 16 + li];
        size_t idx = ((((size_t)bb * 16 + (f0 >> 4) + c) * 32 + (n0 >> 5)) * 64 + L) * 8;
        *(ushort4*)(Qbp + idx) = make_ushort4(o[0], o[1], o[2], o[3]);
        *(ushort4*)(Qbp + idx + 4) = make_ushort4(o[4], o[5], o[6], o[7]);
    } else if (bx < 2656) {
        int t = (bx - 2624) * 256 + tid;
        int lane = t & 63, ci = t >> 6;
        int ot = ci >> 3, fs = ci & 7;
        int qd = lane >> 4, li = lane & 15;
        const float* src = lin_w + (size_t)(ot * 16 + li) * Fc + fs * 32 + qd * 8;
        float4 a = *(const float4*)src;
        float4 b = *(const float4*)(src + 4);
        *(ushort4*)(Wp + (size_t)t * 8) = make_ushort4(f2bf(a.x), f2bf(a.y), f2bf(a.z), f2bf(a.w));
        *(ushort4*)(Wp + (size_t)t * 8 + 4) = make_ushort4(f2bf(b.x), f2bf(b.y), f2bf(b.z), f2bf(b.w));
    } else {
        int i = (bx - 2656) * 256 + tid;   // 512 threads x 16 floats = 8192
        float4 z = make_float4(0.f, 0.f, 0.f, 0.f);
        float4* d = (float4*)(cn + (size_t)i * 16);
        d[0] = z; d[1] = z; d[2] = z; d[3] = z;
        if (bx == 2656 && tid == 0) *klout = 0.f;
    }
}

// ====== fused distance-GEMM: 64 rows/block, 8 waves of 64r x 64c ======
// Exact R5/R8 structure (best warm measurement 63.5us, 0 bank conflicts).
// Grid = 256 = 1 block/CU; acc regs (128) cap waves/SIMD at 2 -> structural
// occupancy ceiling ~21%; do not chase occupancy here.
__global__ __launch_bounds__(512, 2) void cmfma_kernel(
    const float* __restrict__ Q, const unsigned short* __restrict__ Kp,
    const float* __restrict__ k2g, const float* __restrict__ conv_w,
    const int* __restrict__ mask, float* __restrict__ C,
    float* __restrict__ cn, unsigned short* __restrict__ Ctp) {
    __shared__ __align__(16) char uni[36864];   // Ash 32KB main / Tb 36.9KB epilogue
    __shared__ float q2h[8][16];                // per-wave partial q2 (half features)
    __shared__ float msh[64];
    __shared__ float redb[Hc][8][64];           // 16 KB, per-head slot
    __shared__ float mslot[8][64];
    __shared__ float eslot[8][64];
    short* Ash = (short*)uni;                   // 32 frags x 64 lanes x 8 shorts
    short (*Tb)[36] = (short (*)[36])uni;       // epilogue only, per-32-row pass

    const int tid = threadIdx.x;
    const int wv = tid >> 6, L = tid & 63;
    const int qd = L >> 4, li = L & 15;
    const int gr0 = blockIdx.x * 64;
    const int b = gr0 >> 10;

    // ---- cooperative A-frag build: wave wv builds frags (wv>>1)*8+(wv&1)*4+j ----
    {
        int s_ = wv >> 1;
        int ksbase = (wv & 1) * 4;
        const float* qrow = Q + (size_t)(gr0 + s_ * 16 + li) * Fc + qd * 8;
        float q2part = 0.f;
#pragma unroll
        for (int j = 0; j < 4; j++) {
            int ks = ksbase + j;
            float4 a = *(const float4*)(qrow + ks * 32);
            float4 bq = *(const float4*)(qrow + ks * 32 + 4);
            v8s f;
            f[0] = (short)f2bf(a.x);  f[1] = (short)f2bf(a.y);
            f[2] = (short)f2bf(a.z);  f[3] = (short)f2bf(a.w);
            f[4] = (short)f2bf(bq.x); f[5] = (short)f2bf(bq.y);
            f[6] = (short)f2bf(bq.z); f[7] = (short)f2bf(bq.w);
            *(v8s*)&Ash[(((s_ * 8 + ks) * 64) + L) * 8] = f;
            q2part += a.x * a.x + a.y * a.y + a.z * a.z + a.w * a.w +
                      bq.x * bq.x + bq.y * bq.y + bq.z * bq.z + bq.w * bq.w;
        }
        q2part += __shfl_xor(q2part, 16);
        q2part += __shfl_xor(q2part, 32);
        if (qd == 0) q2h[wv][li] = q2part;   // rows of group s_, half-features (wv&1)
    }
    if (tid < 64) msh[tid] = (float)mask[gr0 + tid];

    v4f D[4][4], S[4][4];
#pragma unroll
    for (int s = 0; s < 4; s++)
#pragma unroll
        for (int ct = 0; ct < 4; ct++) {
            D[s][ct] = (v4f){0.f, 0.f, 0.f, 0.f};
            S[s][ct] = (v4f){0.f, 0.f, 0.f, 0.f};
        }

    const unsigned short* kwbase = Kp + (size_t)L * 8;
    v8s Bb[4][4];   // 4-slot rotation, 4 frags (ct) each

#define BLOAD(slot, hn)                                                            \
    do {                                                                           \
        const unsigned short* pb =                                                 \
            kwbase + (size_t)((((hn) >> 3) & 7) * 256 + (wv >> 1) * 64 +           \
                              ((hn) & 7) * 8 + (wv & 1) * 4) * 512;                \
        Bb[slot][0] = *(const v8s*)(pb);                                           \
        Bb[slot][1] = *(const v8s*)(pb + 512);                                     \
        Bb[slot][2] = *(const v8s*)(pb + 1024);                                    \
        Bb[slot][3] = *(const v8s*)(pb + 1536);                                    \
    } while (0)

#define LDA(dst, kk2)                                                              \
    do {                                                                           \
        _Pragma("unroll") for (int s = 0; s < 4; s++)                              \
            dst[s] = *(const v8s*)&Ash[((s * 8 + (kk2)) * 64 + L) * 8];            \
    } while (0)

    BLOAD(0, 0);
    BLOAD(1, 1);
    lds_barrier();   // Ash/q2h/msh visible; B loads stay in flight
    v8s Aa[4], Ab[4];
    LDA(Aa, 0);

#define KSTEP(kk, ACUR, ANXT)                                                      \
    do {                                                                           \
        BLOAD((kk + 2) & 3, h * 8 + kk + 2);                                       \
        LDA(ANXT, ((kk) + 1) & 7);                                                 \
        __builtin_amdgcn_s_setprio(1);                                             \
        _Pragma("unroll") for (int s = 0; s < 4; s++)                              \
            _Pragma("unroll") for (int ct = 0; ct < 4; ct++)                       \
                D[s][ct] = __builtin_amdgcn_mfma_f32_16x16x32_bf16(                \
                    ACUR[s], Bb[(kk) & 3][ct], D[s][ct], 0, 0, 0);                 \
        __builtin_amdgcn_s_setprio(0);                                             \
    } while (0)

    for (int h = 0; h < Hc; ++h) {
        KSTEP(0, Aa, Ab);
        float k2r[4];
#pragma unroll
        for (int ct = 0; ct < 4; ct++)
            k2r[ct] = k2g[h * Kc + wv * 64 + ct * 16 + li];   // k2+1, L2-hit
        KSTEP(1, Ab, Aa); KSTEP(2, Aa, Ab); KSTEP(3, Ab, Aa);
        KSTEP(4, Aa, Ab); KSTEP(5, Ab, Aa); KSTEP(6, Aa, Ab); KSTEP(7, Ab, Aa);

        // ---- per-head transform ----
        float rs[4][4];
        v4f q2v[4];
#pragma unroll
        for (int s = 0; s < 4; s++) {
            q2v[s] = *(const v4f*)&q2h[2 * s][qd * 4];
            v4f t2 = *(const v4f*)&q2h[2 * s + 1][qd * 4];
            q2v[s] += t2;
#pragma unroll
            for (int r = 0; r < 4; r++) rs[s][r] = 0.f;
        }
#pragma unroll
        for (int ct = 0; ct < 4; ct++) {
            float k2v = k2r[ct];
#pragma unroll
            for (int s = 0; s < 4; s++)
#pragma unroll
                for (int r = 0; r < 4; r++) {
                    float x = fmaf(-2.f, D[s][ct][r], q2v[s][r] + k2v);
                    float t = __builtin_amdgcn_rcpf(fmaxf(x, 1.0f));
                    D[s][ct][r] = t;
                    rs[s][r] += t;
                }
        }
#pragma unroll
        for (int s = 0; s < 4; s++)
#pragma unroll
            for (int r = 0; r < 4; r++) {
                rs[s][r] += __shfl_xor(rs[s][r], 1, 16);
                rs[s][r] += __shfl_xor(rs[s][r], 2, 16);
                rs[s][r] += __shfl_xor(rs[s][r], 4, 16);
                rs[s][r] += __shfl_xor(rs[s][r], 8, 16);
            }
        if (li == 0) {
#pragma unroll
            for (int s = 0; s < 4; s++)
#pragma unroll
                for (int r = 0; r < 4; r++)
                    redb[h][wv][s * 16 + qd * 4 + r] = rs[s][r];
        }
        lds_barrier();   // slot h never reused -> single light barrier per head
        float wh = conv_w[h];
#pragma unroll
        for (int s = 0; s < 4; s++) {
            v4f tot = *(const v4f*)&redb[h][0][s * 16 + qd * 4];
#pragma unroll
            for (int w = 1; w < 8; w++) tot += *(const v4f*)&redb[h][w][s * 16 + qd * 4];
#pragma unroll
            for (int r = 0; r < 4; r++) {
                float sc = wh * __builtin_amdgcn_rcpf(tot[r]);
#pragma unroll
                for (int ct = 0; ct < 4; ct++) {
                    S[s][ct][r] += sc * D[s][ct][r];
                    D[s][ct][r] = 0.f;
                }
            }
        }
    }
#undef KSTEP
#undef LDA
#undef BLOAD

    // ---- softmax over 512 cols ----
    float mx[4][4];
#pragma unroll
    for (int s = 0; s < 4; s++)
#pragma unroll
        for (int r = 0; r < 4; r++) {
            float m = S[s][0][r];
            m = fmaxf(m, S[s][1][r]); m = fmaxf(m, S[s][2][r]); m = fmaxf(m, S[s][3][r]);
            m = fmaxf(m, __shfl_xor(m, 1, 16));
            m = fmaxf(m, __shfl_xor(m, 2, 16));
            m = fmaxf(m, __shfl_xor(m, 4, 16));
            m = fmaxf(m, __shfl_xor(m, 8, 16));
            mx[s][r] = m;
        }
    if (li == 0) {
#pragma unroll
        for (int s = 0; s < 4; s++)
#pragma unroll
            for (int r = 0; r < 4; r++) mslot[wv][s * 16 + qd * 4 + r] = mx[s][r];
    }
    lds_barrier();
#pragma unroll
    for (int s = 0; s < 4; s++) {
        v4f m = *(const v4f*)&mslot[0][s * 16 + qd * 4];
#pragma unroll
        for (int w = 1; w < 8; w++) {
            v4f t = *(const v4f*)&mslot[w][s * 16 + qd * 4];
#pragma unroll
            for (int r = 0; r < 4; r++) m[r] = fmaxf(m[r], t[r]);
        }
#pragma unroll
        for (int r = 0; r < 4; r++) mx[s][r] = m[r];
    }
    float es[4][4];
#pragma unroll
    for (int s = 0; s < 4; s++)
#pragma unroll
        for (int r = 0; r < 4; r++) {
            float e0 = __expf(S[s][0][r] - mx[s][r]);
            float e1 = __expf(S[s][1][r] - mx[s][r]);
            float e2 = __expf(S[s][2][r] - mx[s][r]);
            float e3 = __expf(S[s][3][r] - mx[s][r]);
            S[s][0][r] = e0; S[s][1][r] = e1; S[s][2][r] = e2; S[s][3][r] = e3;
            float e = e0 + e1 + e2 + e3;
            e += __shfl_xor(e, 1, 16);
            e += __shfl_xor(e, 2, 16);
            e += __shfl_xor(e, 4, 16);
            e += __shfl_xor(e, 8, 16);
            es[s][r] = e;
        }
    if (li == 0) {
#pragma unroll
        for (int s = 0; s < 4; s++)
#pragma unroll
            for (int r = 0; r < 4; r++) eslot[wv][s * 16 + qd * 4 + r] = es[s][r];
    }
    lds_barrier();
    float inv[4][4];
#pragma unroll
    for (int s = 0; s < 4; s++) {
        v4f tot = *(const v4f*)&eslot[0][s * 16 + qd * 4];
#pragma unroll
        for (int w = 1; w < 8; w++) tot += *(const v4f*)&eslot[w][s * 16 + qd * 4];
        v4f mr = *(const v4f*)&msh[s * 16 + qd * 4];
#pragma unroll
        for (int r = 0; r < 4; r++) inv[s][r] = mr[r] / tot[r];   // masked rows -> 0
    }

    // ---- epilogue: C write + Ctp transpose in two 32-row passes ----
    const int ns0 = (gr0 & 1023) >> 5;
    float colsum[4] = {0.f, 0.f, 0.f, 0.f};
#pragma unroll
    for (int p = 0; p < 2; p++) {
        if (p == 1) lds_barrier();   // pass-0 transpose reads done before refill
#pragma unroll
        for (int ct = 0; ct < 4; ct++) {
            int k = wv * 64 + ct * 16 + li;
#pragma unroll
            for (int s2 = 0; s2 < 2; s2++) {
                int s = p * 2 + s2;
                float cv[4];
#pragma unroll
                for (int r = 0; r < 4; r++) {
                    cv[r] = S[s][ct][r] * inv[s][r];
                    C[(size_t)(gr0 + s * 16 + qd * 4 + r) * Kc + k] = cv[r];
                    colsum[ct] += cv[r];
                }
                short4 t4;
                t4.x = (short)f2bf(cv[0]); t4.y = (short)f2bf(cv[1]);
                t4.z = (short)f2bf(cv[2]); t4.w = (short)f2bf(cv[3]);
                *(short4*)&Tb[k][s2 * 16 + qd * 4] = t4;
            }
        }
        lds_barrier();
        {
            int kt = tid >> 4, klo = tid & 15;
            size_t cbase = (((size_t)b * 32 + kt) * 32 + ns0 + p) * 512;
#pragma unroll
            for (int q2i = 0; q2i < 4; q2i++) {
                short4 lo = *(short4*)&Tb[tid][q2i * 8];
                short4 hi = *(short4*)&Tb[tid][q2i * 8 + 4];
                short4* d = (short4*)(Ctp + cbase + (size_t)(q2i * 16 + klo) * 8);
                d[0] = lo; d[1] = hi;
            }
        }
    }
#pragma unroll
    for (int ct = 0; ct < 4; ct++) {
        int k = wv * 64 + ct * 16 + li;
        float cs = colsum[ct];
        cs += __shfl_xor(cs, 16);
        cs += __shfl_xor(cs, 32);
        if (qd == 0) atomicAdd(&cn[b * Kc + k], cs);
    }
}

// ---- vmfma only: V = C^T Q -> Vp, 8KT x 8FT tiles, 4x4 per wave ----
// kl moved out so its 33.8KB LDS no longer throttles the kl blocks' occupancy.
__global__ __launch_bounds__(256) void klv_kernel(
    const unsigned short* __restrict__ Ctp, const unsigned short* __restrict__ Qbp,
    unsigned short* __restrict__ Vp) {
    __shared__ short Vt[128][132];   // 33.8 KB
    int tid = threadIdx.x;
    int bx = blockIdx.x;
    int w = tid >> 6, L = tid & 63;
    int qd = L >> 4, li = L & 15;
    int wr = w >> 1, wc = w & 1;
    int bb = bx >> 3;          // 16 batches
    int rem = bx & 7;          // ktb(4) x ftb(2)
    int ktb = rem >> 1, ftb = rem & 1;
    int KT0 = ktb * 8 + wr * 4;   // wave covers 4 KT
    int FT0 = ftb * 8 + wc * 4;   // wave covers 4 FT
    const unsigned short* pa[4];
    const unsigned short* pb[4];
#pragma unroll
    for (int a = 0; a < 4; a++)
        pa[a] = Ctp + (((size_t)bb * 32 + KT0 + a) * 32) * 512 + L * 8;
#pragma unroll
    for (int c = 0; c < 4; c++)
        pb[c] = Qbp + (((size_t)bb * 16 + FT0 + c) * 32) * 512 + L * 8;
    v4f acc[4][4];
#pragma unroll
    for (int a = 0; a < 4; a++)
#pragma unroll
        for (int c = 0; c < 4; c++) acc[a][c] = (v4f){0.f, 0.f, 0.f, 0.f};

    v8s A[4], B[4], An[4], Bn[4];
#pragma unroll
    for (int a = 0; a < 4; a++) A[a] = *(const v8s*)pa[a];
#pragma unroll
    for (int c = 0; c < 4; c++) B[c] = *(const v8s*)pb[c];
    for (int ns = 0; ns < 32; ns++) {
        int nn = (ns + 1) & 31;
#pragma unroll
        for (int a = 0; a < 4; a++) An[a] = *(const v8s*)(pa[a] + nn * 512);
#pragma unroll
        for (int c = 0; c < 4; c++) Bn[c] = *(const v8s*)(pb[c] + nn * 512);
#pragma unroll
        for (int a = 0; a < 4; a++)
#pragma unroll
            for (int c = 0; c < 4; c++)
                acc[a][c] = __builtin_amdgcn_mfma_f32_16x16x32_bf16(
                    A[a], B[c], acc[a][c], 0, 0, 0);
#pragma unroll
        for (int a = 0; a < 4; a++) A[a] = An[a];
#pragma unroll
        for (int c = 0; c < 4; c++) B[c] = Bn[c];
    }
#pragma unroll
    for (int a = 0; a < 4; a++)
#pragma unroll
        for (int c = 0; c < 4; c++)
#pragma unroll
            for (int r = 0; r < 4; r++)
                Vt[(wr * 4 + a) * 16 + qd * 4 + r][(wc * 4 + c) * 16 + li] =
                    (short)f2bf(acc[a][c][r]);
    __syncthreads();
    {
        int mtl = tid >> 5, s5 = tid & 31;   // 8 local kt x 32 lanes
        size_t mt_g = (size_t)bb * 32 + ktb * 8 + mtl;
#pragma unroll
        for (int fsl = 0; fsl < 4; fsl++) {
            size_t fs_g = (size_t)ftb * 4 + fsl;
#pragma unroll
            for (int half = 0; half < 2; half++) {
                int L2 = s5 + half * 32;
                int qd2 = L2 >> 4, li2 = L2 & 15;
                short4 x0 = *(short4*)&Vt[mtl * 16 + li2][fsl * 32 + qd2 * 8];
                short4 x1 = *(short4*)&Vt[mtl * 16 + li2][fsl * 32 + qd2 * 8 + 4];
                short4* d = (short4*)(Vp + ((mt_g * 8 + fs_g) * 64 + L2) * 8);
                d[0] = x0; d[1] = x1;
            }
        }
    }
}

// ---- fused: [0,512) out = leaky_relu(Vp @ Wp^T + b); [512,1536) kl ----
// Near-zero static LDS -> kl blocks get full occupancy (was capped at 4/CU
// by the 33.8KB Vt they never used).
__global__ __launch_bounds__(256) void ofma_kernel(
    const unsigned short* __restrict__ Vp, const unsigned short* __restrict__ Wp,
    const float* __restrict__ bias, float* __restrict__ out,
    const float* __restrict__ C, const float* __restrict__ cn,
    float* __restrict__ klout) {
    __shared__ float red[4];
    int tid = threadIdx.x;
    int bx = blockIdx.x;
    if (bx < 512) {
        int w = tid >> 6, L = tid & 63;
        int qd = L >> 4, li = L & 15;
        int wr = w >> 1, wc = w & 1;
        int gx = bx >> 2, gy = bx & 3;
        int MT0 = gx * 4 + wr * 2;
        int OT0 = gy * 4 + wc * 2;
        const unsigned short* pa0 = Vp + ((size_t)MT0 * 8) * 512 + L * 8;
        const unsigned short* pa1 = pa0 + (size_t)8 * 512;
        const unsigned short* pb0 = Wp + ((size_t)OT0 * 8) * 512 + L * 8;
        const unsigned short* pb1 = pb0 + (size_t)8 * 512;
        v4f acc[2][2];
#pragma unroll
        for (int a = 0; a < 2; a++)
#pragma unroll
            for (int c = 0; c < 2; c++) acc[a][c] = (v4f){0.f, 0.f, 0.f, 0.f};
#pragma unroll
        for (int fs = 0; fs < 8; fs++) {
            v8s A0 = *(const v8s*)(pa0 + fs * 512);
            v8s A1 = *(const v8s*)(pa1 + fs * 512);
            v8s B0 = *(const v8s*)(pb0 + fs * 512);
            v8s B1 = *(const v8s*)(pb1 + fs * 512);
            acc[0][0] = __builtin_amdgcn_mfma_f32_16x16x32_bf16(A0, B0, acc[0][0], 0, 0, 0);
            acc[0][1] = __builtin_amdgcn_mfma_f32_16x16x32_bf16(A0, B1, acc[0][1], 0, 0, 0);
            acc[1][0] = __builtin_amdgcn_mfma_f32_16x16x32_bf16(A1, B0, acc[1][0], 0, 0, 0);
            acc[1][1] = __builtin_amdgcn_mfma_f32_16x16x32_bf16(A1, B1, acc[1][1], 0, 0, 0);
        }
#pragma unroll
        for (int c = 0; c < 2; c++) {
            float bv = bias[(OT0 + c) * 16 + li];
#pragma unroll
            for (int a = 0; a < 2; a++)
#pragma unroll
                for (int r = 0; r < 4; r++) {
                    int m = (MT0 + a) * 16 + qd * 4 + r;
                    int o = (OT0 + c) * 16 + li;
                    float x = acc[a][c][r] + bv;
                    out[(size_t)m * DOUTc + o] = x > 0.f ? x : 0.01f * x;
                }
        }
    } else {
        int bk = bx - 512;
        int w = tid >> 6, l = tid & 63;
        int b0 = (bk * 16) >> 10;   // blocks never straddle a batch (1024 % 16 == 0)
        const float* np = cn + b0 * Kc + l * 8;
        v4f n0 = *(const v4f*)np;
        v4f n1 = *(const v4f*)(np + 4);
        float rn[8];
#pragma unroll
        for (int j = 0; j < 4; j++) {
            rn[j] = __builtin_amdgcn_rcpf(n0[j] + EPSc);
            rn[4 + j] = __builtin_amdgcn_rcpf(n1[j] + EPSc);
        }
        float kacc = 0.f;
#pragma unroll
        for (int rr = 0; rr < 4; rr++) {
            int row = bk * 16 + w * 4 + rr;
            const float* cp = C + (size_t)row * Kc + l * 8;
            v4f c0 = *(const v4f*)cp;
            v4f c1 = *(const v4f*)(cp + 4);
            float cc[8] = {c0[0], c0[1], c0[2], c0[3], c1[0], c1[1], c1[2], c1[3]};
            float p[8];
#pragma unroll
            for (int j = 0; j < 8; j++) p[j] = cc[j] * cc[j] * rn[j];
            float s = p[0] + p[1] + p[2] + p[3] + p[4] + p[5] + p[6] + p[7];
            float pn = waveReduceSum(s) + EPSc;
            float rpn = __builtin_amdgcn_rcpf(pn);
#pragma unroll
            for (int j = 0; j < 8; j++) {
                float P = p[j] * rpn;
                kacc += P * __logf((P + EPSc) * __builtin_amdgcn_rcpf(cc[j] + EPSc));
            }
        }
        kacc = waveReduceSum(kacc);
        if (l == 0) red[w] = kacc;
        __syncthreads();
        if (tid == 0)
            atomicAdd(klout, 100.f * (red[0] + red[1] + red[2] + red[3]));
    }
}

extern "C" void kernel_launch(void* const* d_in, const int* in_sizes, int n_in,
                              void* d_out, int out_size, void* d_ws, size_t ws_size,
                              hipStream_t stream) {
    const float* Q = (const float*)d_in[0];
    const float* keys = (const float*)d_in[1];
    const float* conv_w = (const float*)d_in[2];
    const float* lin_w = (const float*)d_in[3];
    const float* lin_b = (const float*)d_in[4];
    const int* mask = (const int*)d_in[5];

    float* out = (float*)d_out;
    float* kl = out + (size_t)Bc * Kc * DOUTc;

    float* ws = (float*)d_ws;
    float* C = ws;                                   // 8,388,608 f
    float* k2 = C + (size_t)Bc * Nc * Kc;            // 4,096 f
    float* cn = k2 + (size_t)Hc * Kc;                // 8,192 f
    unsigned short* Kp = (unsigned short*)(cn + (size_t)Bc * Kc);  // 1,048,576 us
    unsigned short* Ctp = Kp + (size_t)Hc * Kc * Fc;               // 8,388,608 us
    unsigned short* Qbp = Ctp + (size_t)Bc * Nc * Kc;              // 4,194,304 us
    unsigned short* Vp = Qbp + (size_t)Bc * Nc * Fc;               // 2,097,152 us
    unsigned short* Wp = Vp + (size_t)Bc * Kc * Fc;                // 65,536 us

    prep_all<<<2658, 256, 0, stream>>>(Q, keys, lin_w, k2, Kp, Qbp, Wp, cn, kl);
    cmfma_kernel<<<Bc * Nc / 64, 512, 0, stream>>>(Q, Kp, k2, conv_w, mask, C, cn, Ctp);
    klv_kernel<<<128, 256, 0, stream>>>(Ctp, Qbp, Vp);
    ofma_kernel<<<512 + 1024, 256, 0, stream>>>(Vp, Wp, lin_b, out, C, cn, kl);
}

// Round 10
// 172.362 us; speedup vs baseline: 1.0799x; 1.0799x over previous
//
#include <hip/hip_runtime.h>
#include <math.h>

#define Bc 16
#define Nc 1024
#define Fc 256
#define Hc 8
#define Kc 512
#define DOUTc 256
#define EPSc 1e-8f

typedef short v8s __attribute__((ext_vector_type(8)));
typedef float v4f __attribute__((ext_vector_type(4)));

__device__ __forceinline__ float waveReduceSum(float v) {
    v += __shfl_xor(v, 32); v += __shfl_xor(v, 16); v += __shfl_xor(v, 8);
    v += __shfl_xor(v, 4);  v += __shfl_xor(v, 2);  v += __shfl_xor(v, 1);
    return v;
}

__device__ __forceinline__ unsigned short f2bf(float f) {
    unsigned int u = __float_as_uint(f);
    u = (u + 0x7fffu + ((u >> 16) & 1u)) >> 16;   // RNE
    return (unsigned short)u;
}

// CK-style LDS-only barrier: drains lgkmcnt but leaves global loads in flight.
__device__ __forceinline__ void lds_barrier() {
    __builtin_amdgcn_s_waitcnt(0xC07F);   // lgkmcnt(0), vmcnt=63 (no wait), expcnt=7
    __builtin_amdgcn_s_barrier();
}

// ================= preprocessing (Qbp pass now fused into cmfma) ======
// ranges: [0,64)    k2 row sums, 64 rows/block (+1 folded for cmfma)
//         [64,576)  kpack -> Kp   (B-frag order for cmfma)
//         [576,608) wpack -> Wp   (B-frag order for ofma)
//         [608,610) zero cn + kl
__global__ __launch_bounds__(256) void prep_all(
    const float* __restrict__ keys, const float* __restrict__ lin_w,
    float* __restrict__ k2g, unsigned short* __restrict__ Kp,
    unsigned short* __restrict__ Wp,
    float* __restrict__ cn, float* __restrict__ klout) {
    const int bx = blockIdx.x;
    const int tid = threadIdx.x;
    if (bx < 64) {
        int wv = tid >> 6, l = tid & 63;
#pragma unroll 4
        for (int rr = 0; rr < 16; rr++) {
            int row = bx * 64 + wv * 16 + rr;
            float4 v = *(const float4*)(keys + (size_t)row * Fc + l * 4);
            float s = v.x * v.x + v.y * v.y + v.z * v.z + v.w * v.w;
            s = waveReduceSum(s);
            if (l == 0) k2g[row] = s + 1.0f;   // +1 folded: cmfma uses max(d2+1,1)
        }
    } else if (bx < 576) {
        int t = (bx - 64) * 256 + tid;
        int lane = t & 63, ci = t >> 6;
        int ct = ci & 7, ks = (ci >> 3) & 7, wv = (ci >> 6) & 3, h = ci >> 8;
        int qd = lane >> 4, li = lane & 15;
        int col = h * 512 + wv * 128 + ct * 16 + li;
        const float* src = keys + (size_t)col * Fc + ks * 32 + qd * 8;
        float4 a = *(const float4*)src;
        float4 b = *(const float4*)(src + 4);
        *(ushort4*)(Kp + (size_t)t * 8) = make_ushort4(f2bf(a.x), f2bf(a.y), f2bf(a.z), f2bf(a.w));
        *(ushort4*)(Kp + (size_t)t * 8 + 4) = make_ushort4(f2bf(b.x), f2bf(b.y), f2bf(b.z), f2bf(b.w));
    } else if (bx < 608) {
        int t = (bx - 576) * 256 + tid;
        int lane = t & 63, ci = t >> 6;
        int ot = ci >> 3, fs = ci & 7;
        int qd = lane >> 4, li = lane & 15;
        const float* src = lin_w + (size_t)(ot * 16 + li) * Fc + fs * 32 + qd * 8;
        float4 a = *(const float4*)src;
        float4 b = *(const float4*)(src + 4);
        *(ushort4*)(Wp + (size_t)t * 8) = make_ushort4(f2bf(a.x), f2bf(a.y), f2bf(a.z), f2bf(a.w));
        *(ushort4*)(Wp + (size_t)t * 8 + 4) = make_ushort4(f2bf(b.x), f2bf(b.y), f2bf(b.z), f2bf(b.w));
    } else {
        int i = (bx - 608) * 256 + tid;   // 512 threads x 16 floats = 8192
        float4 z = make_float4(0.f, 0.f, 0.f, 0.f);
        float4* d = (float4*)(cn + (size_t)i * 16);
        d[0] = z; d[1] = z; d[2] = z; d[3] = z;
        if (bx == 608 && tid == 0) *klout = 0.f;
    }
}

// ====== fused distance-GEMM: 64 rows/block, 8 waves of 64r x 64c ======
// R5/R8 main loop (best warm 63.1us, 0 bank conflicts) + Qbp emission from
// Ash (the LDS already holds the 64x256 Q tile bf16 -> saves prep's 16MB
// Q re-read and a 2048-block launch).
__global__ __launch_bounds__(512, 2) void cmfma_kernel(
    const float* __restrict__ Q, const unsigned short* __restrict__ Kp,
    const float* __restrict__ k2g, const float* __restrict__ conv_w,
    const int* __restrict__ mask, float* __restrict__ C,
    float* __restrict__ cn, unsigned short* __restrict__ Ctp,
    unsigned short* __restrict__ Qbp) {
    __shared__ __align__(16) char uni[36864];   // Ash 32KB main / Tb 36.9KB epilogue
    __shared__ float q2h[8][16];                // per-wave partial q2 (half features)
    __shared__ float msh[64];
    __shared__ float redb[Hc][8][64];           // 16 KB, per-head slot
    __shared__ float mslot[8][64];
    __shared__ float eslot[8][64];
    short* Ash = (short*)uni;                   // 32 frags x 64 lanes x 8 shorts
    short (*Tb)[36] = (short (*)[36])uni;       // epilogue only, per-32-row pass

    const int tid = threadIdx.x;
    const int wv = tid >> 6, L = tid & 63;
    const int qd = L >> 4, li = L & 15;
    const int gr0 = blockIdx.x * 64;
    const int b = gr0 >> 10;

    // ---- cooperative A-frag build: wave wv builds frags (wv>>1)*8+(wv&1)*4+j ----
    {
        int s_ = wv >> 1;
        int ksbase = (wv & 1) * 4;
        const float* qrow = Q + (size_t)(gr0 + s_ * 16 + li) * Fc + qd * 8;
        float q2part = 0.f;
#pragma unroll
        for (int j = 0; j < 4; j++) {
            int ks = ksbase + j;
            float4 a = *(const float4*)(qrow + ks * 32);
            float4 bq = *(const float4*)(qrow + ks * 32 + 4);
            v8s f;
            f[0] = (short)f2bf(a.x);  f[1] = (short)f2bf(a.y);
            f[2] = (short)f2bf(a.z);  f[3] = (short)f2bf(a.w);
            f[4] = (short)f2bf(bq.x); f[5] = (short)f2bf(bq.y);
            f[6] = (short)f2bf(bq.z); f[7] = (short)f2bf(bq.w);
            *(v8s*)&Ash[(((s_ * 8 + ks) * 64) + L) * 8] = f;
            q2part += a.x * a.x + a.y * a.y + a.z * a.z + a.w * a.w +
                      bq.x * bq.x + bq.y * bq.y + bq.z * bq.z + bq.w * bq.w;
        }
        q2part += __shfl_xor(q2part, 16);
        q2part += __shfl_xor(q2part, 32);
        if (qd == 0) q2h[wv][li] = q2part;   // rows of group s_, half-features (wv&1)
    }
    if (tid < 64) msh[tid] = (float)mask[gr0 + tid];

    v4f D[4][4], S[4][4];
#pragma unroll
    for (int s = 0; s < 4; s++)
#pragma unroll
        for (int ct = 0; ct < 4; ct++) {
            D[s][ct] = (v4f){0.f, 0.f, 0.f, 0.f};
            S[s][ct] = (v4f){0.f, 0.f, 0.f, 0.f};
        }

    const unsigned short* kwbase = Kp + (size_t)L * 8;
    v8s Bb[4][4];   // 4-slot rotation, 4 frags (ct) each

#define BLOAD(slot, hn)                                                            \
    do {                                                                           \
        const unsigned short* pb =                                                 \
            kwbase + (size_t)((((hn) >> 3) & 7) * 256 + (wv >> 1) * 64 +           \
                              ((hn) & 7) * 8 + (wv & 1) * 4) * 512;                \
        Bb[slot][0] = *(const v8s*)(pb);                                           \
        Bb[slot][1] = *(const v8s*)(pb + 512);                                     \
        Bb[slot][2] = *(const v8s*)(pb + 1024);                                    \
        Bb[slot][3] = *(const v8s*)(pb + 1536);                                    \
    } while (0)

#define LDA(dst, kk2)                                                              \
    do {                                                                           \
        _Pragma("unroll") for (int s = 0; s < 4; s++)                              \
            dst[s] = *(const v8s*)&Ash[((s * 8 + (kk2)) * 64 + L) * 8];            \
    } while (0)

    BLOAD(0, 0);
    BLOAD(1, 1);
    lds_barrier();   // Ash/q2h/msh visible; B loads stay in flight
    v8s Aa[4], Ab[4];
    LDA(Aa, 0);

#define KSTEP(kk, ACUR, ANXT)                                                      \
    do {                                                                           \
        BLOAD((kk + 2) & 3, h * 8 + kk + 2);                                       \
        LDA(ANXT, ((kk) + 1) & 7);                                                 \
        __builtin_amdgcn_s_setprio(1);                                             \
        _Pragma("unroll") for (int s = 0; s < 4; s++)                              \
            _Pragma("unroll") for (int ct = 0; ct < 4; ct++)                       \
                D[s][ct] = __builtin_amdgcn_mfma_f32_16x16x32_bf16(                \
                    ACUR[s], Bb[(kk) & 3][ct], D[s][ct], 0, 0, 0);                 \
        __builtin_amdgcn_s_setprio(0);                                             \
    } while (0)

    for (int h = 0; h < Hc; ++h) {
        KSTEP(0, Aa, Ab);
        float k2r[4];
#pragma unroll
        for (int ct = 0; ct < 4; ct++)
            k2r[ct] = k2g[h * Kc + wv * 64 + ct * 16 + li];   // k2+1, L2-hit
        KSTEP(1, Ab, Aa); KSTEP(2, Aa, Ab); KSTEP(3, Ab, Aa);
        KSTEP(4, Aa, Ab); KSTEP(5, Ab, Aa); KSTEP(6, Aa, Ab); KSTEP(7, Ab, Aa);

        // ---- per-head transform ----
        float rs[4][4];
        v4f q2v[4];
#pragma unroll
        for (int s = 0; s < 4; s++) {
            q2v[s] = *(const v4f*)&q2h[2 * s][qd * 4];
            v4f t2 = *(const v4f*)&q2h[2 * s + 1][qd * 4];
            q2v[s] += t2;
#pragma unroll
            for (int r = 0; r < 4; r++) rs[s][r] = 0.f;
        }
#pragma unroll
        for (int ct = 0; ct < 4; ct++) {
            float k2v = k2r[ct];
#pragma unroll
            for (int s = 0; s < 4; s++)
#pragma unroll
                for (int r = 0; r < 4; r++) {
                    float x = fmaf(-2.f, D[s][ct][r], q2v[s][r] + k2v);
                    float t = __builtin_amdgcn_rcpf(fmaxf(x, 1.0f));
                    D[s][ct][r] = t;
                    rs[s][r] += t;
                }
        }
#pragma unroll
        for (int s = 0; s < 4; s++)
#pragma unroll
            for (int r = 0; r < 4; r++) {
                rs[s][r] += __shfl_xor(rs[s][r], 1, 16);
                rs[s][r] += __shfl_xor(rs[s][r], 2, 16);
                rs[s][r] += __shfl_xor(rs[s][r], 4, 16);
                rs[s][r] += __shfl_xor(rs[s][r], 8, 16);
            }
        if (li == 0) {
#pragma unroll
            for (int s = 0; s < 4; s++)
#pragma unroll
                for (int r = 0; r < 4; r++)
                    redb[h][wv][s * 16 + qd * 4 + r] = rs[s][r];
        }
        lds_barrier();   // slot h never reused -> single light barrier per head
        float wh = conv_w[h];
#pragma unroll
        for (int s = 0; s < 4; s++) {
            v4f tot = *(const v4f*)&redb[h][0][s * 16 + qd * 4];
#pragma unroll
            for (int w = 1; w < 8; w++) tot += *(const v4f*)&redb[h][w][s * 16 + qd * 4];
#pragma unroll
            for (int r = 0; r < 4; r++) {
                float sc = wh * __builtin_amdgcn_rcpf(tot[r]);
#pragma unroll
                for (int ct = 0; ct < 4; ct++) {
                    S[s][ct][r] += sc * D[s][ct][r];
                    D[s][ct][r] = 0.f;
                }
            }
        }
    }
#undef KSTEP
#undef LDA
#undef BLOAD

    // ---- emit Qbp (vmfma B-frags) straight from Ash ----
    // frag (ns_local, ft): lane L2=(qd2,li2) elem j = Q_bf16[gr0+ns_local*32+qd2*8+j][ft*16+li2]
    // Ash addr for (row r, col c): ((r>>4)*8 + (c>>5))*64 + ((c>>3)&3)*16 + (r&15), elem c&7
    {
        int fi = tid >> 4;              // 0..31 = ns_local*16 + ft
        int nsl = fi >> 4, ft = fi & 15;
        int sub = tid & 15;
        size_t qb = (((size_t)b * 16 + ft) * 32 + ((gr0 & 1023) >> 5) + nsl) * 64;
        const unsigned short* ash = (const unsigned short*)Ash;
#pragma unroll
        for (int l4 = 0; l4 < 4; l4++) {
            int L2 = sub * 4 + l4;
            int qd2 = L2 >> 4, li2 = L2 & 15;
            int c = ft * 16 + li2;
            int cbase = ((c >> 5) * 64 + ((c >> 3) & 3) * 16) * 8 + (c & 7);
            unsigned short o[8];
#pragma unroll
            for (int j = 0; j < 8; j++) {
                int r = nsl * 32 + qd2 * 8 + j;
                o[j] = ash[((r >> 4) * 8) * 512 + cbase + (r & 15) * 8];
            }
            *(ushort4*)(Qbp + (qb + L2) * 8) = make_ushort4(o[0], o[1], o[2], o[3]);
            *(ushort4*)(Qbp + (qb + L2) * 8 + 4) = make_ushort4(o[4], o[5], o[6], o[7]);
        }
    }

    // ---- softmax over 512 cols ----
    float mx[4][4];
#pragma unroll
    for (int s = 0; s < 4; s++)
#pragma unroll
        for (int r = 0; r < 4; r++) {
            float m = S[s][0][r];
            m = fmaxf(m, S[s][1][r]); m = fmaxf(m, S[s][2][r]); m = fmaxf(m, S[s][3][r]);
            m = fmaxf(m, __shfl_xor(m, 1, 16));
            m = fmaxf(m, __shfl_xor(m, 2, 16));
            m = fmaxf(m, __shfl_xor(m, 4, 16));
            m = fmaxf(m, __shfl_xor(m, 8, 16));
            mx[s][r] = m;
        }
    if (li == 0) {
#pragma unroll
        for (int s = 0; s < 4; s++)
#pragma unroll
            for (int r = 0; r < 4; r++) mslot[wv][s * 16 + qd * 4 + r] = mx[s][r];
    }
    lds_barrier();
#pragma unroll
    for (int s = 0; s < 4; s++) {
        v4f m = *(const v4f*)&mslot[0][s * 16 + qd * 4];
#pragma unroll
        for (int w = 1; w < 8; w++) {
            v4f t = *(const v4f*)&mslot[w][s * 16 + qd * 4];
#pragma unroll
            for (int r = 0; r < 4; r++) m[r] = fmaxf(m[r], t[r]);
        }
#pragma unroll
        for (int r = 0; r < 4; r++) mx[s][r] = m[r];
    }
    float es[4][4];
#pragma unroll
    for (int s = 0; s < 4; s++)
#pragma unroll
        for (int r = 0; r < 4; r++) {
            float e0 = __expf(S[s][0][r] - mx[s][r]);
            float e1 = __expf(S[s][1][r] - mx[s][r]);
            float e2 = __expf(S[s][2][r] - mx[s][r]);
            float e3 = __expf(S[s][3][r] - mx[s][r]);
            S[s][0][r] = e0; S[s][1][r] = e1; S[s][2][r] = e2; S[s][3][r] = e3;
            float e = e0 + e1 + e2 + e3;
            e += __shfl_xor(e, 1, 16);
            e += __shfl_xor(e, 2, 16);
            e += __shfl_xor(e, 4, 16);
            e += __shfl_xor(e, 8, 16);
            es[s][r] = e;
        }
    if (li == 0) {
#pragma unroll
        for (int s = 0; s < 4; s++)
#pragma unroll
            for (int r = 0; r < 4; r++) eslot[wv][s * 16 + qd * 4 + r] = es[s][r];
    }
    lds_barrier();
    float inv[4][4];
#pragma unroll
    for (int s = 0; s < 4; s++) {
        v4f tot = *(const v4f*)&eslot[0][s * 16 + qd * 4];
#pragma unroll
        for (int w = 1; w < 8; w++) tot += *(const v4f*)&eslot[w][s * 16 + qd * 4];
        v4f mr = *(const v4f*)&msh[s * 16 + qd * 4];
#pragma unroll
        for (int r = 0; r < 4; r++) inv[s][r] = mr[r] / tot[r];   // masked rows -> 0
    }

    // ---- epilogue: C write + Ctp transpose in two 32-row passes ----
    const int ns0 = (gr0 & 1023) >> 5;
    float colsum[4] = {0.f, 0.f, 0.f, 0.f};
#pragma unroll
    for (int p = 0; p < 2; p++) {
        if (p == 1) lds_barrier();   // pass-0 transpose reads done before refill
#pragma unroll
        for (int ct = 0; ct < 4; ct++) {
            int k = wv * 64 + ct * 16 + li;
#pragma unroll
            for (int s2 = 0; s2 < 2; s2++) {
                int s = p * 2 + s2;
                float cv[4];
#pragma unroll
                for (int r = 0; r < 4; r++) {
                    cv[r] = S[s][ct][r] * inv[s][r];
                    C[(size_t)(gr0 + s * 16 + qd * 4 + r) * Kc + k] = cv[r];
                    colsum[ct] += cv[r];
                }
                short4 t4;
                t4.x = (short)f2bf(cv[0]); t4.y = (short)f2bf(cv[1]);
                t4.z = (short)f2bf(cv[2]); t4.w = (short)f2bf(cv[3]);
                *(short4*)&Tb[k][s2 * 16 + qd * 4] = t4;
            }
        }
        lds_barrier();
        {
            int kt = tid >> 4, klo = tid & 15;
            size_t cbase = (((size_t)b * 32 + kt) * 32 + ns0 + p) * 512;
#pragma unroll
            for (int q2i = 0; q2i < 4; q2i++) {
                short4 lo = *(short4*)&Tb[tid][q2i * 8];
                short4 hi = *(short4*)&Tb[tid][q2i * 8 + 4];
                short4* d = (short4*)(Ctp + cbase + (size_t)(q2i * 16 + klo) * 8);
                d[0] = lo; d[1] = hi;
            }
        }
    }
#pragma unroll
    for (int ct = 0; ct < 4; ct++) {
        int k = wv * 64 + ct * 16 + li;
        float cs = colsum[ct];
        cs += __shfl_xor(cs, 16);
        cs += __shfl_xor(cs, 32);
        if (qd == 0) atomicAdd(&cn[b * Kc + k], cs);
    }
}

// ---- fused: [0,512) vmfma (V = C^T Q -> Vp bf16 packed); [512,1536) kl ----
// Exact R2 structure (best measured middle section): 2x2 tiles/wave, 9.7KB
// Vt so co-resident kl blocks keep full occupancy AND overlap vmfma.
__global__ __launch_bounds__(256) void klv_kernel(
    const unsigned short* __restrict__ Ctp, const unsigned short* __restrict__ Qbp,
    unsigned short* __restrict__ Vp, const float* __restrict__ C,
    const float* __restrict__ cn, float* __restrict__ klout) {
    __shared__ short Vt[64][76];
    __shared__ float red[4];
    int tid = threadIdx.x;
    int bx = blockIdx.x;
    if (bx < 512) {
        int w = tid >> 6, L = tid & 63;
        int qd = L >> 4, li = L & 15;
        int wr = w >> 1, wc = w & 1;
        int bb = bx >> 5;
        int rem = bx & 31;
        int ktb = rem >> 2, ftb = rem & 3;
        int KT0 = ktb * 4 + wr * 2;
        int FT0 = ftb * 4 + wc * 2;
        const unsigned short* pa0 = Ctp + (((size_t)bb * 32 + KT0) * 32) * 512 + L * 8;
        const unsigned short* pa1 = pa0 + (size_t)32 * 512;
        const unsigned short* pb0 = Qbp + (((size_t)bb * 16 + FT0) * 32) * 512 + L * 8;
        const unsigned short* pb1 = pb0 + (size_t)32 * 512;
        v4f acc[2][2];
#pragma unroll
        for (int a = 0; a < 2; a++)
#pragma unroll
            for (int c = 0; c < 2; c++) acc[a][c] = (v4f){0.f, 0.f, 0.f, 0.f};

        v8s A0 = *(const v8s*)pa0, A1 = *(const v8s*)pa1;
        v8s B0 = *(const v8s*)pb0, B1 = *(const v8s*)pb1;
        for (int ns = 0; ns < 32; ns++) {
            int nsn = (ns + 1) & 31;
            v8s A0n = *(const v8s*)(pa0 + nsn * 512);
            v8s A1n = *(const v8s*)(pa1 + nsn * 512);
            v8s B0n = *(const v8s*)(pb0 + nsn * 512);
            v8s B1n = *(const v8s*)(pb1 + nsn * 512);
            acc[0][0] = __builtin_amdgcn_mfma_f32_16x16x32_bf16(A0, B0, acc[0][0], 0, 0, 0);
            acc[0][1] = __builtin_amdgcn_mfma_f32_16x16x32_bf16(A0, B1, acc[0][1], 0, 0, 0);
            acc[1][0] = __builtin_amdgcn_mfma_f32_16x16x32_bf16(A1, B0, acc[1][0], 0, 0, 0);
            acc[1][1] = __builtin_amdgcn_mfma_f32_16x16x32_bf16(A1, B1, acc[1][1], 0, 0, 0);
            A0 = A0n; A1 = A1n; B0 = B0n; B1 = B1n;
        }
#pragma unroll
        for (int a = 0; a < 2; a++)
#pragma unroll
            for (int c = 0; c < 2; c++)
#pragma unroll
                for (int r = 0; r < 4; r++)
                    Vt[(wr * 2 + a) * 16 + qd * 4 + r][(wc * 2 + c) * 16 + li] =
                        (short)f2bf(acc[a][c][r]);
        __syncthreads();
        {
            int ci = tid >> 5, s5 = tid & 31;
            int mtl = ci >> 1, fsl = ci & 1;
            size_t mt_g = (size_t)bb * 32 + ktb * 4 + mtl;
            size_t fs_g = (size_t)ftb * 2 + fsl;
#pragma unroll
            for (int half = 0; half < 2; half++) {
                int L2 = s5 + half * 32;
                int qd2 = L2 >> 4, li2 = L2 & 15;
                short4 x0 = *(short4*)&Vt[mtl * 16 + li2][fsl * 32 + qd2 * 8];
                short4 x1 = *(short4*)&Vt[mtl * 16 + li2][fsl * 32 + qd2 * 8 + 4];
                short4* d = (short4*)(Vp + ((mt_g * 8 + fs_g) * 64 + L2) * 8);
                d[0] = x0; d[1] = x1;
            }
        }
    } else {
        int bk = bx - 512;
        int w = tid >> 6, l = tid & 63;
        int b0 = (bk * 16) >> 10;   // blocks never straddle a batch (1024 % 16 == 0)
        const float* np = cn + b0 * Kc + l * 8;
        v4f n0 = *(const v4f*)np;
        v4f n1 = *(const v4f*)(np + 4);
        float rn[8];
#pragma unroll
        for (int j = 0; j < 4; j++) {
            rn[j] = __builtin_amdgcn_rcpf(n0[j] + EPSc);
            rn[4 + j] = __builtin_amdgcn_rcpf(n1[j] + EPSc);
        }
        float kacc = 0.f;
#pragma unroll
        for (int rr = 0; rr < 4; rr++) {
            int row = bk * 16 + w * 4 + rr;
            const float* cp = C + (size_t)row * Kc + l * 8;
            v4f c0 = *(const v4f*)cp;
            v4f c1 = *(const v4f*)(cp + 4);
            float cc[8] = {c0[0], c0[1], c0[2], c0[3], c1[0], c1[1], c1[2], c1[3]};
            float p[8];
#pragma unroll
            for (int j = 0; j < 8; j++) p[j] = cc[j] * cc[j] * rn[j];
            float s = p[0] + p[1] + p[2] + p[3] + p[4] + p[5] + p[6] + p[7];
            float pn = waveReduceSum(s) + EPSc;
            float rpn = __builtin_amdgcn_rcpf(pn);
#pragma unroll
            for (int j = 0; j < 8; j++) {
                float P = p[j] * rpn;
                kacc += P * __logf((P + EPSc) * __builtin_amdgcn_rcpf(cc[j] + EPSc));
            }
        }
        kacc = waveReduceSum(kacc);
        if (l == 0) red[w] = kacc;
        __syncthreads();
        if (tid == 0)
            atomicAdd(klout, 100.f * (red[0] + red[1] + red[2] + red[3]));
    }
}

// ---- out = leaky_relu(Vp @ Wp^T + b) via MFMA ----
__global__ __launch_bounds__(256) void ofma_kernel(
    const unsigned short* __restrict__ Vp, const unsigned short* __restrict__ Wp,
    const float* __restrict__ bias, float* __restrict__ out) {
    int tid = threadIdx.x;
    int w = tid >> 6, L = tid & 63;
    int qd = L >> 4, li = L & 15;
    int wr = w >> 1, wc = w & 1;
    int MT0 = blockIdx.x * 4 + wr * 2;
    int OT0 = blockIdx.y * 4 + wc * 2;
    const unsigned short* pa0 = Vp + ((size_t)MT0 * 8) * 512 + L * 8;
    const unsigned short* pa1 = pa0 + (size_t)8 * 512;
    const unsigned short* pb0 = Wp + ((size_t)OT0 * 8) * 512 + L * 8;
    const unsigned short* pb1 = pb0 + (size_t)8 * 512;
    v4f acc[2][2];
#pragma unroll
    for (int a = 0; a < 2; a++)
#pragma unroll
        for (int c = 0; c < 2; c++) acc[a][c] = (v4f){0.f, 0.f, 0.f, 0.f};
#pragma unroll
    for (int fs = 0; fs < 8; fs++) {
        v8s A0 = *(const v8s*)(pa0 + fs * 512);
        v8s A1 = *(const v8s*)(pa1 + fs * 512);
        v8s B0 = *(const v8s*)(pb0 + fs * 512);
        v8s B1 = *(const v8s*)(pb1 + fs * 512);
        acc[0][0] = __builtin_amdgcn_mfma_f32_16x16x32_bf16(A0, B0, acc[0][0], 0, 0, 0);
        acc[0][1] = __builtin_amdgcn_mfma_f32_16x16x32_bf16(A0, B1, acc[0][1], 0, 0, 0);
        acc[1][0] = __builtin_amdgcn_mfma_f32_16x16x32_bf16(A1, B0, acc[1][0], 0, 0, 0);
        acc[1][1] = __builtin_amdgcn_mfma_f32_16x16x32_bf16(A1, B1, acc[1][1], 0, 0, 0);
    }
#pragma unroll
    for (int c = 0; c < 2; c++) {
        float bv = bias[(OT0 + c) * 16 + li];
#pragma unroll
        for (int a = 0; a < 2; a++)
#pragma unroll
            for (int r = 0; r < 4; r++) {
                int m = (MT0 + a) * 16 + qd * 4 + r;
                int o = (OT0 + c) * 16 + li;
                float x = acc[a][c][r] + bv;
                out[(size_t)m * DOUTc + o] = x > 0.f ? x : 0.01f * x;
            }
    }
}

extern "C" void kernel_launch(void* const* d_in, const int* in_sizes, int n_in,
                              void* d_out, int out_size, void* d_ws, size_t ws_size,
                              hipStream_t stream) {
    const float* Q = (const float*)d_in[0];
    const float* keys = (const float*)d_in[1];
    const float* conv_w = (const float*)d_in[2];
    const float* lin_w = (const float*)d_in[3];
    const float* lin_b = (const float*)d_in[4];
    const int* mask = (const int*)d_in[5];

    float* out = (float*)d_out;
    float* kl = out + (size_t)Bc * Kc * DOUTc;

    float* ws = (float*)d_ws;
    float* C = ws;                                   // 8,388,608 f
    float* k2 = C + (size_t)Bc * Nc * Kc;            // 4,096 f
    float* cn = k2 + (size_t)Hc * Kc;                // 8,192 f
    unsigned short* Kp = (unsigned short*)(cn + (size_t)Bc * Kc);  // 1,048,576 us
    unsigned short* Ctp = Kp + (size_t)Hc * Kc * Fc;               // 8,388,608 us
    unsigned short* Qbp = Ctp + (size_t)Bc * Nc * Kc;              // 4,194,304 us
    unsigned short* Vp = Qbp + (size_t)Bc * Nc * Fc;               // 2,097,152 us
    unsigned short* Wp = Vp + (size_t)Bc * Kc * Fc;                // 65,536 us

    prep_all<<<610, 256, 0, stream>>>(keys, lin_w, k2, Kp, Wp, cn, kl);
    cmfma_kernel<<<Bc * Nc / 64, 512, 0, stream>>>(Q, Kp, k2, conv_w, mask, C, cn, Ctp, Qbp);
    klv_kernel<<<1536, 256, 0, stream>>>(Ctp, Qbp, Vp, C, cn, kl);
    ofma_kernel<<<dim3(Bc * Kc / 64, DOUTc / 64), 256, 0, stream>>>(Vp, Wp, lin_b, out);
}

// Round 11
// 166.881 us; speedup vs baseline: 1.1153x; 1.0328x over previous
//
#include <hip/hip_runtime.h>
#include <math.h>

#define Bc 16
#define Nc 1024
#define Fc 256
#define Hc 8
#define Kc 512
#define DOUTc 256
#define EPSc 1e-8f

typedef short v8s __attribute__((ext_vector_type(8)));
typedef float v4f __attribute__((ext_vector_type(4)));

__device__ __forceinline__ float waveReduceSum(float v) {
    v += __shfl_xor(v, 32); v += __shfl_xor(v, 16); v += __shfl_xor(v, 8);
    v += __shfl_xor(v, 4);  v += __shfl_xor(v, 2);  v += __shfl_xor(v, 1);
    return v;
}

__device__ __forceinline__ unsigned short f2bf(float f) {
    unsigned int u = __float_as_uint(f);
    u = (u + 0x7fffu + ((u >> 16) & 1u)) >> 16;   // RNE
    return (unsigned short)u;
}

// CK-style LDS-only barrier: drains lgkmcnt but leaves global loads in flight.
__device__ __forceinline__ void lds_barrier() {
    __builtin_amdgcn_s_waitcnt(0xC07F);   // lgkmcnt(0), vmcnt=63 (no wait), expcnt=7
    __builtin_amdgcn_s_barrier();
}

// ================= preprocessing (Qbp pass fused into cmfma) ======
// ranges: [0,64)    k2 row sums, 64 rows/block (+1 folded for cmfma)
//         [64,576)  kpack -> Kp   (B-frag order for cmfma)
//         [576,608) wpack -> Wp   (B-frag order for ofma)
//         [608,610) zero cn + kl
__global__ __launch_bounds__(256) void prep_all(
    const float* __restrict__ keys, const float* __restrict__ lin_w,
    float* __restrict__ k2g, unsigned short* __restrict__ Kp,
    unsigned short* __restrict__ Wp,
    float* __restrict__ cn, float* __restrict__ klout) {
    const int bx = blockIdx.x;
    const int tid = threadIdx.x;
    if (bx < 64) {
        int wv = tid >> 6, l = tid & 63;
#pragma unroll 4
        for (int rr = 0; rr < 16; rr++) {
            int row = bx * 64 + wv * 16 + rr;
            float4 v = *(const float4*)(keys + (size_t)row * Fc + l * 4);
            float s = v.x * v.x + v.y * v.y + v.z * v.z + v.w * v.w;
            s = waveReduceSum(s);
            if (l == 0) k2g[row] = s + 1.0f;   // +1 folded: cmfma uses max(d2+1,1)
        }
    } else if (bx < 576) {
        int t = (bx - 64) * 256 + tid;
        int lane = t & 63, ci = t >> 6;
        int ct = ci & 7, ks = (ci >> 3) & 7, wv = (ci >> 6) & 3, h = ci >> 8;
        int qd = lane >> 4, li = lane & 15;
        int col = h * 512 + wv * 128 + ct * 16 + li;
        const float* src = keys + (size_t)col * Fc + ks * 32 + qd * 8;
        float4 a = *(const float4*)src;
        float4 b = *(const float4*)(src + 4);
        *(ushort4*)(Kp + (size_t)t * 8) = make_ushort4(f2bf(a.x), f2bf(a.y), f2bf(a.z), f2bf(a.w));
        *(ushort4*)(Kp + (size_t)t * 8 + 4) = make_ushort4(f2bf(b.x), f2bf(b.y), f2bf(b.z), f2bf(b.w));
    } else if (bx < 608) {
        int t = (bx - 576) * 256 + tid;
        int lane = t & 63, ci = t >> 6;
        int ot = ci >> 3, fs = ci & 7;
        int qd = lane >> 4, li = lane & 15;
        const float* src = lin_w + (size_t)(ot * 16 + li) * Fc + fs * 32 + qd * 8;
        float4 a = *(const float4*)src;
        float4 b = *(const float4*)(src + 4);
        *(ushort4*)(Wp + (size_t)t * 8) = make_ushort4(f2bf(a.x), f2bf(a.y), f2bf(a.z), f2bf(a.w));
        *(ushort4*)(Wp + (size_t)t * 8 + 4) = make_ushort4(f2bf(b.x), f2bf(b.y), f2bf(b.z), f2bf(b.w));
    } else {
        int i = (bx - 608) * 256 + tid;   // 512 threads x 16 floats = 8192
        float4 z = make_float4(0.f, 0.f, 0.f, 0.f);
        float4* d = (float4*)(cn + (size_t)i * 16);
        d[0] = z; d[1] = z; d[2] = z; d[3] = z;
        if (bx == 608 && tid == 0) *klout = 0.f;
    }
}

// ====== fused distance-GEMM: 64 rows/block, 8 waves of 64r x 64c ======
// R5/R8 main loop (best warm 63.1us, 0 bank conflicts) + Qbp emission from
// Ash (saves prep's 16MB Q re-read and a 2048-block launch; costs ~2.5us).
__global__ __launch_bounds__(512, 2) void cmfma_kernel(
    const float* __restrict__ Q, const unsigned short* __restrict__ Kp,
    const float* __restrict__ k2g, const float* __restrict__ conv_w,
    const int* __restrict__ mask, float* __restrict__ C,
    float* __restrict__ cn, unsigned short* __restrict__ Ctp,
    unsigned short* __restrict__ Qbp) {
    __shared__ __align__(16) char uni[36864];   // Ash 32KB main / Tb 36.9KB epilogue
    __shared__ float q2h[8][16];                // per-wave partial q2 (half features)
    __shared__ float msh[64];
    __shared__ float redb[Hc][8][64];           // 16 KB, per-head slot
    __shared__ float mslot[8][64];
    __shared__ float eslot[8][64];
    short* Ash = (short*)uni;                   // 32 frags x 64 lanes x 8 shorts
    short (*Tb)[36] = (short (*)[36])uni;       // epilogue only, per-32-row pass

    const int tid = threadIdx.x;
    const int wv = tid >> 6, L = tid & 63;
    const int qd = L >> 4, li = L & 15;
    const int gr0 = blockIdx.x * 64;
    const int b = gr0 >> 10;

    // ---- cooperative A-frag build: wave wv builds frags (wv>>1)*8+(wv&1)*4+j ----
    {
        int s_ = wv >> 1;
        int ksbase = (wv & 1) * 4;
        const float* qrow = Q + (size_t)(gr0 + s_ * 16 + li) * Fc + qd * 8;
        float q2part = 0.f;
#pragma unroll
        for (int j = 0; j < 4; j++) {
            int ks = ksbase + j;
            float4 a = *(const float4*)(qrow + ks * 32);
            float4 bq = *(const float4*)(qrow + ks * 32 + 4);
            v8s f;
            f[0] = (short)f2bf(a.x);  f[1] = (short)f2bf(a.y);
            f[2] = (short)f2bf(a.z);  f[3] = (short)f2bf(a.w);
            f[4] = (short)f2bf(bq.x); f[5] = (short)f2bf(bq.y);
            f[6] = (short)f2bf(bq.z); f[7] = (short)f2bf(bq.w);
            *(v8s*)&Ash[(((s_ * 8 + ks) * 64) + L) * 8] = f;
            q2part += a.x * a.x + a.y * a.y + a.z * a.z + a.w * a.w +
                      bq.x * bq.x + bq.y * bq.y + bq.z * bq.z + bq.w * bq.w;
        }
        q2part += __shfl_xor(q2part, 16);
        q2part += __shfl_xor(q2part, 32);
        if (qd == 0) q2h[wv][li] = q2part;   // rows of group s_, half-features (wv&1)
    }
    if (tid < 64) msh[tid] = (float)mask[gr0 + tid];

    v4f D[4][4], S[4][4];
#pragma unroll
    for (int s = 0; s < 4; s++)
#pragma unroll
        for (int ct = 0; ct < 4; ct++) {
            D[s][ct] = (v4f){0.f, 0.f, 0.f, 0.f};
            S[s][ct] = (v4f){0.f, 0.f, 0.f, 0.f};
        }

    const unsigned short* kwbase = Kp + (size_t)L * 8;
    v8s Bb[4][4];   // 4-slot rotation, 4 frags (ct) each

#define BLOAD(slot, hn)                                                            \
    do {                                                                           \
        const unsigned short* pb =                                                 \
            kwbase + (size_t)((((hn) >> 3) & 7) * 256 + (wv >> 1) * 64 +           \
                              ((hn) & 7) * 8 + (wv & 1) * 4) * 512;                \
        Bb[slot][0] = *(const v8s*)(pb);                                           \
        Bb[slot][1] = *(const v8s*)(pb + 512);                                     \
        Bb[slot][2] = *(const v8s*)(pb + 1024);                                    \
        Bb[slot][3] = *(const v8s*)(pb + 1536);                                    \
    } while (0)

#define LDA(dst, kk2)                                                              \
    do {                                                                           \
        _Pragma("unroll") for (int s = 0; s < 4; s++)                              \
            dst[s] = *(const v8s*)&Ash[((s * 8 + (kk2)) * 64 + L) * 8];            \
    } while (0)

    BLOAD(0, 0);
    BLOAD(1, 1);
    lds_barrier();   // Ash/q2h/msh visible; B loads stay in flight
    v8s Aa[4], Ab[4];
    LDA(Aa, 0);

#define KSTEP(kk, ACUR, ANXT)                                                      \
    do {                                                                           \
        BLOAD((kk + 2) & 3, h * 8 + kk + 2);                                       \
        LDA(ANXT, ((kk) + 1) & 7);                                                 \
        __builtin_amdgcn_s_setprio(1);                                             \
        _Pragma("unroll") for (int s = 0; s < 4; s++)                              \
            _Pragma("unroll") for (int ct = 0; ct < 4; ct++)                       \
                D[s][ct] = __builtin_amdgcn_mfma_f32_16x16x32_bf16(                \
                    ACUR[s], Bb[(kk) & 3][ct], D[s][ct], 0, 0, 0);                 \
        __builtin_amdgcn_s_setprio(0);                                             \
    } while (0)

    for (int h = 0; h < Hc; ++h) {
        KSTEP(0, Aa, Ab);
        float k2r[4];
#pragma unroll
        for (int ct = 0; ct < 4; ct++)
            k2r[ct] = k2g[h * Kc + wv * 64 + ct * 16 + li];   // k2+1, L2-hit
        KSTEP(1, Ab, Aa); KSTEP(2, Aa, Ab); KSTEP(3, Ab, Aa);
        KSTEP(4, Aa, Ab); KSTEP(5, Ab, Aa); KSTEP(6, Aa, Ab); KSTEP(7, Ab, Aa);

        // ---- per-head transform ----
        float rs[4][4];
        v4f q2v[4];
#pragma unroll
        for (int s = 0; s < 4; s++) {
            q2v[s] = *(const v4f*)&q2h[2 * s][qd * 4];
            v4f t2 = *(const v4f*)&q2h[2 * s + 1][qd * 4];
            q2v[s] += t2;
#pragma unroll
            for (int r = 0; r < 4; r++) rs[s][r] = 0.f;
        }
#pragma unroll
        for (int ct = 0; ct < 4; ct++) {
            float k2v = k2r[ct];
#pragma unroll
            for (int s = 0; s < 4; s++)
#pragma unroll
                for (int r = 0; r < 4; r++) {
                    float x = fmaf(-2.f, D[s][ct][r], q2v[s][r] + k2v);
                    float t = __builtin_amdgcn_rcpf(fmaxf(x, 1.0f));
                    D[s][ct][r] = t;
                    rs[s][r] += t;
                }
        }
#pragma unroll
        for (int s = 0; s < 4; s++)
#pragma unroll
            for (int r = 0; r < 4; r++) {
                rs[s][r] += __shfl_xor(rs[s][r], 1, 16);
                rs[s][r] += __shfl_xor(rs[s][r], 2, 16);
                rs[s][r] += __shfl_xor(rs[s][r], 4, 16);
                rs[s][r] += __shfl_xor(rs[s][r], 8, 16);
            }
        if (li == 0) {
#pragma unroll
            for (int s = 0; s < 4; s++)
#pragma unroll
                for (int r = 0; r < 4; r++)
                    redb[h][wv][s * 16 + qd * 4 + r] = rs[s][r];
        }
        lds_barrier();   // slot h never reused -> single light barrier per head
        float wh = conv_w[h];
#pragma unroll
        for (int s = 0; s < 4; s++) {
            v4f tot = *(const v4f*)&redb[h][0][s * 16 + qd * 4];
#pragma unroll
            for (int w = 1; w < 8; w++) tot += *(const v4f*)&redb[h][w][s * 16 + qd * 4];
#pragma unroll
            for (int r = 0; r < 4; r++) {
                float sc = wh * __builtin_amdgcn_rcpf(tot[r]);
#pragma unroll
                for (int ct = 0; ct < 4; ct++) {
                    S[s][ct][r] += sc * D[s][ct][r];
                    D[s][ct][r] = 0.f;
                }
            }
        }
    }
#undef KSTEP
#undef LDA
#undef BLOAD

    // ---- emit Qbp (vmfma B-frags) straight from Ash ----
    {
        int fi = tid >> 4;              // 0..31 = ns_local*16 + ft
        int nsl = fi >> 4, ft = fi & 15;
        int sub = tid & 15;
        size_t qb = (((size_t)b * 16 + ft) * 32 + ((gr0 & 1023) >> 5) + nsl) * 64;
        const unsigned short* ash = (const unsigned short*)Ash;
#pragma unroll
        for (int l4 = 0; l4 < 4; l4++) {
            int L2 = sub * 4 + l4;
            int qd2 = L2 >> 4, li2 = L2 & 15;
            int c = ft * 16 + li2;
            int cbase = ((c >> 5) * 64 + ((c >> 3) & 3) * 16) * 8 + (c & 7);
            unsigned short o[8];
#pragma unroll
            for (int j = 0; j < 8; j++) {
                int r = nsl * 32 + qd2 * 8 + j;
                o[j] = ash[((r >> 4) * 8) * 512 + cbase + (r & 15) * 8];
            }
            *(ushort4*)(Qbp + (qb + L2) * 8) = make_ushort4(o[0], o[1], o[2], o[3]);
            *(ushort4*)(Qbp + (qb + L2) * 8 + 4) = make_ushort4(o[4], o[5], o[6], o[7]);
        }
    }

    // ---- softmax over 512 cols ----
    float mx[4][4];
#pragma unroll
    for (int s = 0; s < 4; s++)
#pragma unroll
        for (int r = 0; r < 4; r++) {
            float m = S[s][0][r];
            m = fmaxf(m, S[s][1][r]); m = fmaxf(m, S[s][2][r]); m = fmaxf(m, S[s][3][r]);
            m = fmaxf(m, __shfl_xor(m, 1, 16));
            m = fmaxf(m, __shfl_xor(m, 2, 16));
            m = fmaxf(m, __shfl_xor(m, 4, 16));
            m = fmaxf(m, __shfl_xor(m, 8, 16));
            mx[s][r] = m;
        }
    if (li == 0) {
#pragma unroll
        for (int s = 0; s < 4; s++)
#pragma unroll
            for (int r = 0; r < 4; r++) mslot[wv][s * 16 + qd * 4 + r] = mx[s][r];
    }
    lds_barrier();
#pragma unroll
    for (int s = 0; s < 4; s++) {
        v4f m = *(const v4f*)&mslot[0][s * 16 + qd * 4];
#pragma unroll
        for (int w = 1; w < 8; w++) {
            v4f t = *(const v4f*)&mslot[w][s * 16 + qd * 4];
#pragma unroll
            for (int r = 0; r < 4; r++) m[r] = fmaxf(m[r], t[r]);
        }
#pragma unroll
        for (int r = 0; r < 4; r++) mx[s][r] = m[r];
    }
    float es[4][4];
#pragma unroll
    for (int s = 0; s < 4; s++)
#pragma unroll
        for (int r = 0; r < 4; r++) {
            float e0 = __expf(S[s][0][r] - mx[s][r]);
            float e1 = __expf(S[s][1][r] - mx[s][r]);
            float e2 = __expf(S[s][2][r] - mx[s][r]);
            float e3 = __expf(S[s][3][r] - mx[s][r]);
            S[s][0][r] = e0; S[s][1][r] = e1; S[s][2][r] = e2; S[s][3][r] = e3;
            float e = e0 + e1 + e2 + e3;
            e += __shfl_xor(e, 1, 16);
            e += __shfl_xor(e, 2, 16);
            e += __shfl_xor(e, 4, 16);
            e += __shfl_xor(e, 8, 16);
            es[s][r] = e;
        }
    if (li == 0) {
#pragma unroll
        for (int s = 0; s < 4; s++)
#pragma unroll
            for (int r = 0; r < 4; r++) eslot[wv][s * 16 + qd * 4 + r] = es[s][r];
    }
    lds_barrier();
    float inv[4][4];
#pragma unroll
    for (int s = 0; s < 4; s++) {
        v4f tot = *(const v4f*)&eslot[0][s * 16 + qd * 4];
#pragma unroll
        for (int w = 1; w < 8; w++) tot += *(const v4f*)&eslot[w][s * 16 + qd * 4];
        v4f mr = *(const v4f*)&msh[s * 16 + qd * 4];
#pragma unroll
        for (int r = 0; r < 4; r++) inv[s][r] = mr[r] / tot[r];   // masked rows -> 0
    }

    // ---- epilogue: C write + Ctp transpose in two 32-row passes ----
    const int ns0 = (gr0 & 1023) >> 5;
    float colsum[4] = {0.f, 0.f, 0.f, 0.f};
#pragma unroll
    for (int p = 0; p < 2; p++) {
        if (p == 1) lds_barrier();   // pass-0 transpose reads done before refill
#pragma unroll
        for (int ct = 0; ct < 4; ct++) {
            int k = wv * 64 + ct * 16 + li;
#pragma unroll
            for (int s2 = 0; s2 < 2; s2++) {
                int s = p * 2 + s2;
                float cv[4];
#pragma unroll
                for (int r = 0; r < 4; r++) {
                    cv[r] = S[s][ct][r] * inv[s][r];
                    C[(size_t)(gr0 + s * 16 + qd * 4 + r) * Kc + k] = cv[r];
                    colsum[ct] += cv[r];
                }
                short4 t4;
                t4.x = (short)f2bf(cv[0]); t4.y = (short)f2bf(cv[1]);
                t4.z = (short)f2bf(cv[2]); t4.w = (short)f2bf(cv[3]);
                *(short4*)&Tb[k][s2 * 16 + qd * 4] = t4;
            }
        }
        lds_barrier();
        {
            int kt = tid >> 4, klo = tid & 15;
            size_t cbase = (((size_t)b * 32 + kt) * 32 + ns0 + p) * 512;
#pragma unroll
            for (int q2i = 0; q2i < 4; q2i++) {
                short4 lo = *(short4*)&Tb[tid][q2i * 8];
                short4 hi = *(short4*)&Tb[tid][q2i * 8 + 4];
                short4* d = (short4*)(Ctp + cbase + (size_t)(q2i * 16 + klo) * 8);
                d[0] = lo; d[1] = hi;
            }
        }
    }
#pragma unroll
    for (int ct = 0; ct < 4; ct++) {
        int k = wv * 64 + ct * 16 + li;
        float cs = colsum[ct];
        cs += __shfl_xor(cs, 16);
        cs += __shfl_xor(cs, 32);
        if (qd == 0) atomicAdd(&cn[b * Kc + k], cs);
    }
}

// ---- fused: [0,512) vmfma (V = C^T Q -> Vp); [512,1536) kl ----
// R2 structure + XCD-locality swizzles:
//  vmfma: XCD x gets batches {2x,2x+1} -> 3MB working set fits 4MB L2.
//  kl: block for rows bk*16 lands on the XCD that wrote those C rows.
__global__ __launch_bounds__(256) void klv_kernel(
    const unsigned short* __restrict__ Ctp, const unsigned short* __restrict__ Qbp,
    unsigned short* __restrict__ Vp, const float* __restrict__ C,
    const float* __restrict__ cn, float* __restrict__ klout) {
    __shared__ short Vt[64][76];
    __shared__ float red[4];
    int tid = threadIdx.x;
    int bxr = blockIdx.x;
    if (bxr < 512) {
        // swizzle: i = g*8+x -> bb = 2x + (g>>5), rem = g&31  (bijective)
        int x = bxr & 7, g = bxr >> 3;
        int bb = 2 * x + (g >> 5);
        int rem = g & 31;
        int w = tid >> 6, L = tid & 63;
        int qd = L >> 4, li = L & 15;
        int wr = w >> 1, wc = w & 1;
        int ktb = rem >> 2, ftb = rem & 3;
        int KT0 = ktb * 4 + wr * 2;
        int FT0 = ftb * 4 + wc * 2;
        const unsigned short* pa0 = Ctp + (((size_t)bb * 32 + KT0) * 32) * 512 + L * 8;
        const unsigned short* pa1 = pa0 + (size_t)32 * 512;
        const unsigned short* pb0 = Qbp + (((size_t)bb * 16 + FT0) * 32) * 512 + L * 8;
        const unsigned short* pb1 = pb0 + (size_t)32 * 512;
        v4f acc[2][2];
#pragma unroll
        for (int a = 0; a < 2; a++)
#pragma unroll
            for (int c = 0; c < 2; c++) acc[a][c] = (v4f){0.f, 0.f, 0.f, 0.f};

        v8s A0 = *(const v8s*)pa0, A1 = *(const v8s*)pa1;
        v8s B0 = *(const v8s*)pb0, B1 = *(const v8s*)pb1;
        for (int ns = 0; ns < 32; ns++) {
            int nsn = (ns + 1) & 31;
            v8s A0n = *(const v8s*)(pa0 + nsn * 512);
            v8s A1n = *(const v8s*)(pa1 + nsn * 512);
            v8s B0n = *(const v8s*)(pb0 + nsn * 512);
            v8s B1n = *(const v8s*)(pb1 + nsn * 512);
            acc[0][0] = __builtin_amdgcn_mfma_f32_16x16x32_bf16(A0, B0, acc[0][0], 0, 0, 0);
            acc[0][1] = __builtin_amdgcn_mfma_f32_16x16x32_bf16(A0, B1, acc[0][1], 0, 0, 0);
            acc[1][0] = __builtin_amdgcn_mfma_f32_16x16x32_bf16(A1, B0, acc[1][0], 0, 0, 0);
            acc[1][1] = __builtin_amdgcn_mfma_f32_16x16x32_bf16(A1, B1, acc[1][1], 0, 0, 0);
            A0 = A0n; A1 = A1n; B0 = B0n; B1 = B1n;
        }
#pragma unroll
        for (int a = 0; a < 2; a++)
#pragma unroll
            for (int c = 0; c < 2; c++)
#pragma unroll
                for (int r = 0; r < 4; r++)
                    Vt[(wr * 2 + a) * 16 + qd * 4 + r][(wc * 2 + c) * 16 + li] =
                        (short)f2bf(acc[a][c][r]);
        __syncthreads();
        {
            int ci = tid >> 5, s5 = tid & 31;
            int mtl = ci >> 1, fsl = ci & 1;
            size_t mt_g = (size_t)bb * 32 + ktb * 4 + mtl;
            size_t fs_g = (size_t)ftb * 2 + fsl;
#pragma unroll
            for (int half = 0; half < 2; half++) {
                int L2 = s5 + half * 32;
                int qd2 = L2 >> 4, li2 = L2 & 15;
                short4 x0 = *(short4*)&Vt[mtl * 16 + li2][fsl * 32 + qd2 * 8];
                short4 x1 = *(short4*)&Vt[mtl * 16 + li2][fsl * 32 + qd2 * 8 + 4];
                short4* d = (short4*)(Vp + ((mt_g * 8 + fs_g) * 64 + L2) * 8);
                d[0] = x0; d[1] = x1;
            }
        }
    } else {
        // swizzle: j = g*8+x -> bk = (g>>2)*32 + x*4 + (g&3)  (bijective)
        // puts this block on the XCD that wrote C rows [bk*16, bk*16+16)
        int j = bxr - 512;
        int x = j & 7, g = j >> 3;
        int bk = (g >> 2) * 32 + x * 4 + (g & 3);
        int w = tid >> 6, l = tid & 63;
        int b0 = (bk * 16) >> 10;   // blocks never straddle a batch (1024 % 16 == 0)
        const float* np = cn + b0 * Kc + l * 8;
        v4f n0 = *(const v4f*)np;
        v4f n1 = *(const v4f*)(np + 4);
        float rn[8];
#pragma unroll
        for (int jj = 0; jj < 4; jj++) {
            rn[jj] = __builtin_amdgcn_rcpf(n0[jj] + EPSc);
            rn[4 + jj] = __builtin_amdgcn_rcpf(n1[jj] + EPSc);
        }
        float kacc = 0.f;
#pragma unroll
        for (int rr = 0; rr < 4; rr++) {
            int row = bk * 16 + w * 4 + rr;
            const float* cp = C + (size_t)row * Kc + l * 8;
            v4f c0 = *(const v4f*)cp;
            v4f c1 = *(const v4f*)(cp + 4);
            float cc[8] = {c0[0], c0[1], c0[2], c0[3], c1[0], c1[1], c1[2], c1[3]};
            float p[8];
#pragma unroll
            for (int jj = 0; jj < 8; jj++) p[jj] = cc[jj] * cc[jj] * rn[jj];
            float s = p[0] + p[1] + p[2] + p[3] + p[4] + p[5] + p[6] + p[7];
            float pn = waveReduceSum(s) + EPSc;
            float rpn = __builtin_amdgcn_rcpf(pn);
#pragma unroll
            for (int jj = 0; jj < 8; jj++) {
                float P = p[jj] * rpn;
                kacc += P * __logf((P + EPSc) * __builtin_amdgcn_rcpf(cc[jj] + EPSc));
            }
        }
        kacc = waveReduceSum(kacc);
        if (l == 0) red[w] = kacc;
        __syncthreads();
        if (tid == 0)
            atomicAdd(klout, 100.f * (red[0] + red[1] + red[2] + red[3]));
    }
}

// ---- out = leaky_relu(Vp @ Wp^T + b) via MFMA ----
__global__ __launch_bounds__(256) void ofma_kernel(
    const unsigned short* __restrict__ Vp, const unsigned short* __restrict__ Wp,
    const float* __restrict__ bias, float* __restrict__ out) {
    int tid = threadIdx.x;
    int w = tid >> 6, L = tid & 63;
    int qd = L >> 4, li = L & 15;
    int wr = w >> 1, wc = w & 1;
    int MT0 = blockIdx.x * 4 + wr * 2;
    int OT0 = blockIdx.y * 4 + wc * 2;
    const unsigned short* pa0 = Vp + ((size_t)MT0 * 8) * 512 + L * 8;
    const unsigned short* pa1 = pa0 + (size_t)8 * 512;
    const unsigned short* pb0 = Wp + ((size_t)OT0 * 8) * 512 + L * 8;
    const unsigned short* pb1 = pb0 + (size_t)8 * 512;
    v4f acc[2][2];
#pragma unroll
    for (int a = 0; a < 2; a++)
#pragma unroll
        for (int c = 0; c < 2; c++) acc[a][c] = (v4f){0.f, 0.f, 0.f, 0.f};
#pragma unroll
    for (int fs = 0; fs < 8; fs++) {
        v8s A0 = *(const v8s*)(pa0 + fs * 512);
        v8s A1 = *(const v8s*)(pa1 + fs * 512);
        v8s B0 = *(const v8s*)(pb0 + fs * 512);
        v8s B1 = *(const v8s*)(pb1 + fs * 512);
        acc[0][0] = __builtin_amdgcn_mfma_f32_16x16x32_bf16(A0, B0, acc[0][0], 0, 0, 0);
        acc[0][1] = __builtin_amdgcn_mfma_f32_16x16x32_bf16(A0, B1, acc[0][1], 0, 0, 0);
        acc[1][0] = __builtin_amdgcn_mfma_f32_16x16x32_bf16(A1, B0, acc[1][0], 0, 0, 0);
        acc[1][1] = __builtin_amdgcn_mfma_f32_16x16x32_bf16(A1, B1, acc[1][1], 0, 0, 0);
    }
#pragma unroll
    for (int c = 0; c < 2; c++) {
        float bv = bias[(OT0 + c) * 16 + li];
#pragma unroll
        for (int a = 0; a < 2; a++)
#pragma unroll
            for (int r = 0; r < 4; r++) {
                int m = (MT0 + a) * 16 + qd * 4 + r;
                int o = (OT0 + c) * 16 + li;
                float x = acc[a][c][r] + bv;
                out[(size_t)m * DOUTc + o] = x > 0.f ? x : 0.01f * x;
            }
    }
}

extern "C" void kernel_launch(void* const* d_in, const int* in_sizes, int n_in,
                              void* d_out, int out_size, void* d_ws, size_t ws_size,
                              hipStream_t stream) {
    const float* Q = (const float*)d_in[0];
    const float* keys = (const float*)d_in[1];
    const float* conv_w = (const float*)d_in[2];
    const float* lin_w = (const float*)d_in[3];
    const float* lin_b = (const float*)d_in[4];
    const int* mask = (const int*)d_in[5];

    float* out = (float*)d_out;
    float* kl = out + (size_t)Bc * Kc * DOUTc;

    float* ws = (float*)d_ws;
    float* C = ws;                                   // 8,388,608 f
    float* k2 = C + (size_t)Bc * Nc * Kc;            // 4,096 f
    float* cn = k2 + (size_t)Hc * Kc;                // 8,192 f
    unsigned short* Kp = (unsigned short*)(cn + (size_t)Bc * Kc);  // 1,048,576 us
    unsigned short* Ctp = Kp + (size_t)Hc * Kc * Fc;               // 8,388,608 us
    unsigned short* Qbp = Ctp + (size_t)Bc * Nc * Kc;              // 4,194,304 us
    unsigned short* Vp = Qbp + (size_t)Bc * Nc * Fc;               // 2,097,152 us
    unsigned short* Wp = Vp + (size_t)Bc * Kc * Fc;                // 65,536 us

    prep_all<<<610, 256, 0, stream>>>(keys, lin_w, k2, Kp, Wp, cn, kl);
    cmfma_kernel<<<Bc * Nc / 64, 512, 0, stream>>>(Q, Kp, k2, conv_w, mask, C, cn, Ctp, Qbp);
    klv_kernel<<<1536, 256, 0, stream>>>(Ctp, Qbp, Vp, C, cn, kl);
    ofma_kernel<<<dim3(Bc * Kc / 64, DOUTc / 64), 256, 0, stream>>>(Vp, Wp, lin_b, out);
}